// Round 5
// baseline (28.017 us; speedup 1.0000x reference)
//
#include <hip/hip_runtime.h>
#include <math.h>

// Problem constants (fixed by setup_inputs): h [8,4096,512] f32, patch_ids [8,4096] i32 sorted,
// P=1024, k=4. Output [8,1024,512] f32.
#define BS   8
#define SEQ  4096
#define DIM  512
#define NP   1024
#define KTOP 4
#define GRP  4                 // patches per block
#define NEGINF_C (-1.0e9f)

typedef float f32x4 __attribute__((ext_vector_type(4)));

// ---------------------------------------------------------------------------
// Branchless distinct-insert into descending 4-list (top-4 DISTINCT values).
// Reference's iterate-max-knock-ties loop == distinct values in desc order;
// maintaining top-4-distinct incrementally is order-independent and idempotent
// under re-insertion of seen values.
// ---------------------------------------------------------------------------
__device__ __forceinline__ void ins4(float v, float& m0, float& m1, float& m2, float& m3) {
    const bool dup = (v == m0) | (v == m1) | (v == m2) | (v == m3);
    v = dup ? -INFINITY : v;   // -inf never displaces anything
    float a;
    a = fmaxf(m0, v); v = fminf(m0, v); m0 = a;
    a = fmaxf(m1, v); v = fminf(m1, v); m1 = a;
    a = fmaxf(m2, v); v = fminf(m2, v); m2 = a;
    m3 = fmaxf(m3, v);
}

// ---------------------------------------------------------------------------
// One block per (b, group of GRP patches). 128 threads x f32x4 = 512 dims.
// Streams the group's contiguous token range once, sequentially, with 1-deep
// prefetch; flushes a patch's mean on id-change (wave-uniform branch).
// ---------------------------------------------------------------------------
__global__ __launch_bounds__(128) void topk_pool_grouped(const float* __restrict__ h,
                                                         const int* __restrict__ pid,
                                                         float* __restrict__ out) {
    const int blk = blockIdx.x;
    const int b   = blk / (NP / GRP);
    const int g   = blk % (NP / GRP);
    const int p0  = g * GRP;
    const int tid = threadIdx.x;
    const int* ids = pid + b * SEQ;

    // lower_bound over sorted ids: lane0 -> p0, lane1 -> p0+GRP.
    // 13 steps = ceil(log2(4097)): final interval size 0 (12 was off-by-one).
    const int target = p0 + (tid & 1) * GRP;
    int lo = 0, hi = SEQ;
    #pragma unroll
    for (int s = 0; s < 13; ++s) {
        const int mid  = (lo + hi) >> 1;
        const int midc = (mid < SEQ) ? mid : (SEQ - 1);   // guard OOB when lo==hi==SEQ
        const bool go  = (ids[midc] < target) & (mid < hi);
        lo = go ? mid + 1 : lo;
        hi = go ? hi : mid;
    }
    const int start = __shfl(lo, 0);
    const int end   = __shfl(lo, 1);

    f32x4*       outg = (f32x4*)(out + ((size_t)b * NP + p0) * DIM);
    const f32x4* hb   = (const f32x4*)(h + (size_t)b * SEQ * DIM);
    const f32x4  zv   = (f32x4){0.f, 0.f, 0.f, 0.f};

    // top-4-distinct state for 4 owned dims; static indexing only
    float m[4][4];
    #pragma unroll
    for (int d = 0; d < 4; ++d)
        #pragma unroll
        for (int i = 0; i < 4; ++i) m[d][i] = -INFINITY;
    int cnt = 0;
    int cur = p0 - 1;            // no active patch yet

    if (start < end) {
        int   t  = start;
        f32x4 v  = hb[(size_t)t * (DIM / 4) + tid];
        int   id = ids[t];
        while (t < end) {
            const int   tn  = (t + 1 < end) ? t + 1 : t;      // clamped prefetch
            const f32x4 vn  = hb[(size_t)tn * (DIM / 4) + tid];
            const int   idn = ids[tn];

            if (id != cur) {                                   // wave-uniform
                if (cur >= p0) {                               // flush finished patch
                    const int n  = (cnt < KTOP) ? cnt : KTOP;
                    const float nf = (float)n;
                    float s[4];
                    #pragma unroll
                    for (int d = 0; d < 4; ++d) {
                        float acc = 0.0f;
                        #pragma unroll
                        for (int i = 0; i < KTOP; ++i)
                            if (i < n) acc += (m[d][i] == -INFINITY) ? NEGINF_C : m[d][i];
                        s[d] = acc / nf;
                    }
                    __builtin_nontemporal_store((f32x4){s[0], s[1], s[2], s[3]},
                                                &outg[(cur - p0) * (DIM / 4) + tid]);
                }
                for (int q = (cur < p0 ? p0 : cur + 1); q < id; ++q)   // empty patches
                    __builtin_nontemporal_store(zv, &outg[(q - p0) * (DIM / 4) + tid]);
                cur = id; cnt = 0;
                #pragma unroll
                for (int d = 0; d < 4; ++d)
                    #pragma unroll
                    for (int i = 0; i < 4; ++i) m[d][i] = -INFINITY;
            }

            ins4(v.x, m[0][0], m[0][1], m[0][2], m[0][3]);
            ins4(v.y, m[1][0], m[1][1], m[1][2], m[1][3]);
            ins4(v.z, m[2][0], m[2][1], m[2][2], m[2][3]);
            ins4(v.w, m[3][0], m[3][1], m[3][2], m[3][3]);
            ++cnt;

            v = vn; id = idn; ++t;
        }
        // flush last active patch (cur >= p0 guaranteed since start<end)
        {
            const int n  = (cnt < KTOP) ? cnt : KTOP;
            const float nf = (float)n;
            float s[4];
            #pragma unroll
            for (int d = 0; d < 4; ++d) {
                float acc = 0.0f;
                #pragma unroll
                for (int i = 0; i < KTOP; ++i)
                    if (i < n) acc += (m[d][i] == -INFINITY) ? NEGINF_C : m[d][i];
                s[d] = acc / nf;
            }
            __builtin_nontemporal_store((f32x4){s[0], s[1], s[2], s[3]},
                                        &outg[(cur - p0) * (DIM / 4) + tid]);
        }
        for (int q = cur + 1; q < p0 + GRP; ++q)                // trailing empties
            __builtin_nontemporal_store(zv, &outg[(q - p0) * (DIM / 4) + tid]);
    } else {
        #pragma unroll
        for (int q = p0; q < p0 + GRP; ++q)                     // whole group empty
            __builtin_nontemporal_store(zv, &outg[(q - p0) * (DIM / 4) + tid]);
    }
}

// ---------------------------------------------------------------------------
extern "C" void kernel_launch(void* const* d_in, const int* in_sizes, int n_in,
                              void* d_out, int out_size, void* d_ws, size_t ws_size,
                              hipStream_t stream) {
    const float* h   = (const float*)d_in[0];
    const int*   pid = (const int*)d_in[1];
    float*       out = (float*)d_out;
    (void)d_ws; (void)ws_size;

    topk_pool_grouped<<<dim3(BS * (NP / GRP)), dim3(128), 0, stream>>>(h, pid, out);
}